// Round 2
// baseline (1267.897 us; speedup 1.0000x reference)
//
#include <hip/hip_runtime.h>

#define NPTS 1000000
#define KOFF 27
#define NWG_CONV 7813            // ceil(N/128)
#define NWAVES (NWG_CONV * 4)

typedef __bf16 bf16x8 __attribute__((ext_vector_type(8)));
typedef __bf16 bf16x4 __attribute__((ext_vector_type(4)));
typedef float f32x4 __attribute__((ext_vector_type(4)));

// ---------------- Kernel 1: xb[N+1][64] = bf16(concat(feats, time_emb[batch_idx])) ; row N = 0
__global__ __launch_bounds__(256) void build_x_kernel(
    const float* __restrict__ feats, const float* __restrict__ time_emb,
    const int* __restrict__ batch_idx, __bf16* __restrict__ xb)
{
    const long g = (long)blockIdx.x * 256 + threadIdx.x;
    if (g >= (long)(NPTS + 1) * 16) return;
    const int row = (int)(g >> 4);
    const int c = ((int)g & 15) << 2;
    bf16x4 o;
    if (row < NPTS) {
        f32x4 v;
        if (c < 32) {
            v = __builtin_nontemporal_load((const f32x4*)(feats + (size_t)row * 32 + c));
        } else {
            const int b = batch_idx[row];
            v = *(const f32x4*)(time_emb + (size_t)b * 32 + (c - 32));
        }
        o[0] = (__bf16)v[0]; o[1] = (__bf16)v[1];
        o[2] = (__bf16)v[2]; o[3] = (__bf16)v[3];
    } else {
        o[0] = o[1] = o[2] = o[3] = (__bf16)0.0f;
    }
    *(bf16x4*)(xb + (size_t)row * 64 + c) = o;   // normal store: keep xb L2/L3-resident
}

// ---------------- Kernel 2: WbT[k][cout][cin] = bf16(W[k][cin][cout])
__global__ __launch_bounds__(256) void wtrans_kernel(
    const float* __restrict__ W, __bf16* __restrict__ wbt)
{
    const int g = blockIdx.x * 256 + threadIdx.x;
    if (g >= KOFF * 4096) return;
    const int k = g >> 12;
    const int rem = g & 4095;
    const int co = rem >> 6;
    const int ci = rem & 63;
    wbt[g] = (__bf16)W[(k << 12) + (ci << 6) + co];
}

// ---------------- Kernel 3: gather-GEMM conv, operand-swapped MFMA.
// D = Wt_frag * x_frag  ->  D col (lane&15) = point, D row (quad*4+j) = cout.
// 4 waves/WG, no LDS, no barriers. 1-deep A-gather pipeline, 2-deep idx prefetch.
__global__ __launch_bounds__(256) void conv_kernel(
    const __bf16* __restrict__ xb, const __bf16* __restrict__ wbt,
    const int* __restrict__ nbr_idx, const int* __restrict__ nbr_valid,
    float* __restrict__ out, float* __restrict__ partials)
{
    const int tid  = threadIdx.x;
    const int wave = tid >> 6;
    const int lane = tid & 63;
    const int l15  = lane & 15;
    const int quad = lane >> 4;
    const int wg   = blockIdx.x;
    const int R0   = wg * 128 + wave * 32;
    const int row0 = R0 + l15;        // point group 0
    const int row1 = row0 + 16;       // point group 1

    f32x4 acc[2][4];
#pragma unroll
    for (int m = 0; m < 2; ++m)
#pragma unroll
        for (int ct = 0; ct < 4; ++ct)
            acc[m][ct] = (f32x4){0.f, 0.f, 0.f, 0.f};

    const int r0c = row0 < NPTS ? row0 : NPTS - 1;
    const int r1c = row1 < NPTS ? row1 : NPTS - 1;
    const bool ok0 = row0 < NPTS;
    const bool ok1 = row1 < NPTS;

    // ---- pipeline prologue: idx[0] -> A[0] issued; idx[1] prefetched
    int ci0 = __builtin_nontemporal_load(nbr_idx + r0c);
    int ci1 = __builtin_nontemporal_load(nbr_idx + r1c);
    int cv0 = __builtin_nontemporal_load(nbr_valid + r0c);
    int cv1 = __builtin_nontemporal_load(nbr_valid + r1c);
    {
        const int g0 = (cv0 && ok0) ? ci0 : NPTS;
        const int g1 = (cv1 && ok1) ? ci1 : NPTS;
        ci0 = g0; ci1 = g1;
    }
    const bf16x8* ap0 = (const bf16x8*)(xb + (size_t)ci0 * 64) + quad;
    const bf16x8* ap1 = (const bf16x8*)(xb + (size_t)ci1 * 64) + quad;
    bf16x8 A0lo = ap0[0], A0hi = ap0[4];
    bf16x8 A1lo = ap1[0], A1hi = ap1[4];

    int ni0 = __builtin_nontemporal_load(nbr_idx + NPTS + r0c);
    int ni1 = __builtin_nontemporal_load(nbr_idx + NPTS + r1c);
    int nv0 = __builtin_nontemporal_load(nbr_valid + NPTS + r0c);
    int nv1 = __builtin_nontemporal_load(nbr_valid + NPTS + r1c);

    for (int k = 0; k < KOFF; ++k) {
        // ---- issue A-gathers for k+1 (overlap with this iteration's MFMA)
        int gn0 = NPTS, gn1 = NPTS;
        if (k < KOFF - 1) {
            gn0 = (nv0 && ok0) ? ni0 : NPTS;
            gn1 = (nv1 && ok1) ? ni1 : NPTS;
        }
        const bf16x8* np0 = (const bf16x8*)(xb + (size_t)gn0 * 64) + quad;
        const bf16x8* np1 = (const bf16x8*)(xb + (size_t)gn1 * 64) + quad;
        bf16x8 N0lo = np0[0], N0hi = np0[4];
        bf16x8 N1lo = np1[0], N1hi = np1[4];

        // ---- prefetch idx/valid for k+2 (nontemporal: single-use stream)
        if (k < KOFF - 2) {
            const int kb2 = (k + 2) * NPTS;
            ni0 = __builtin_nontemporal_load(nbr_idx + kb2 + r0c);
            ni1 = __builtin_nontemporal_load(nbr_idx + kb2 + r1c);
            nv0 = __builtin_nontemporal_load(nbr_valid + kb2 + r0c);
            nv1 = __builtin_nontemporal_load(nbr_valid + kb2 + r1c);
        }

        // ---- B fragments (W^T, heavily reused -> normal cached loads)
        const bf16x8* wb8 = (const bf16x8*)wbt + (size_t)k * 512 + l15 * 8 + quad;
#pragma unroll
        for (int ct = 0; ct < 4; ++ct) {
            const bf16x8 b0 = wb8[ct * 128];       // cin 0..31
            const bf16x8 b1 = wb8[ct * 128 + 4];   // cin 32..63
            acc[0][ct] = __builtin_amdgcn_mfma_f32_16x16x32_bf16(b0, A0lo, acc[0][ct], 0, 0, 0);
            acc[0][ct] = __builtin_amdgcn_mfma_f32_16x16x32_bf16(b1, A0hi, acc[0][ct], 0, 0, 0);
            acc[1][ct] = __builtin_amdgcn_mfma_f32_16x16x32_bf16(b0, A1lo, acc[1][ct], 0, 0, 0);
            acc[1][ct] = __builtin_amdgcn_mfma_f32_16x16x32_bf16(b1, A1hi, acc[1][ct], 0, 0, 0);
        }

        A0lo = N0lo; A0hi = N0hi; A1lo = N1lo; A1hi = N1hi;
    }

    // ---- store pre-BN f32: lane holds couts {ct*16+quad*4+j} of point (group m, l15)
    //      -> f32x4 stores; 4 quads form a full contiguous 64B line per point row per ct.
#pragma unroll
    for (int m = 0; m < 2; ++m) {
        const int p = R0 + m * 16 + l15;
        if (p < NPTS) {
            float* pp = out + (size_t)p * 64 + quad * 4;
#pragma unroll
            for (int ct = 0; ct < 4; ++ct)
                __builtin_nontemporal_store(acc[m][ct], (f32x4*)(pp + ct * 16));
        }
    }

    // ---- BN partials: sum over the 16 points (l15 lanes) per cout; tail rows are 0.
    const size_t pb = ((size_t)wg * 4 + wave) * 128;
#pragma unroll
    for (int ct = 0; ct < 4; ++ct) {
        f32x4 sv, qv;
#pragma unroll
        for (int j = 0; j < 4; ++j) {
            float s  = acc[0][ct][j] + acc[1][ct][j];
            float ss = acc[0][ct][j] * acc[0][ct][j] + acc[1][ct][j] * acc[1][ct][j];
            s += __shfl_xor(s, 1);  ss += __shfl_xor(ss, 1);
            s += __shfl_xor(s, 2);  ss += __shfl_xor(ss, 2);
            s += __shfl_xor(s, 4);  ss += __shfl_xor(ss, 4);
            s += __shfl_xor(s, 8);  ss += __shfl_xor(ss, 8);
            sv[j] = s; qv[j] = ss;
        }
        if (l15 == 0) {
            __builtin_nontemporal_store(sv, (f32x4*)(partials + pb + ct * 16 + quad * 4));
            __builtin_nontemporal_store(qv, (f32x4*)(partials + pb + 64 + ct * 16 + quad * 4));
        }
    }
}

// ---------------- Kernel 4: reduce partials [NWAVES][128] -> p2 [128][128]
__global__ __launch_bounds__(256) void bn_pass1(
    const float* __restrict__ partials, float* __restrict__ p2)
{
    __shared__ float lds[256];
    const int tid = threadIdx.x;
    const int c = tid & 127;
    const int half = tid >> 7;
    float s = 0.f;
    for (int r = blockIdx.x * 2 + half; r < NWAVES; r += 256)
        s += __builtin_nontemporal_load(partials + (size_t)r * 128 + c);
    lds[tid] = s;
    __syncthreads();
    if (tid < 128) p2[blockIdx.x * 128 + tid] = lds[tid] + lds[tid + 128];
}

// ---------------- Kernel 5: finalize BN scale/shift (64 + 64 floats)
__global__ void bn_pass2(const float* __restrict__ p2, const float* __restrict__ gamma,
                         const float* __restrict__ beta, float* __restrict__ bn)
{
    __shared__ float lds[128];
    const int t = threadIdx.x;
    float s = 0.f;
    for (int b = 0; b < 128; ++b) s += p2[b * 128 + t];
    lds[t] = s;
    __syncthreads();
    if (t < 64) {
        const float inv_n = 1.0f / (float)NPTS;
        const float mean = lds[t] * inv_n;
        const float var = lds[t + 64] * inv_n - mean * mean;
        const float scale = rsqrtf(var + 1e-5f) * gamma[t];
        bn[t] = scale;
        bn[64 + t] = beta[t] - mean * scale;   // conv bias cancels under BN; omitted
    }
}

// ---------------- Kernel 6: y = silu(pre*scale + shift), in-place on d_out (nt streams)
__global__ __launch_bounds__(256) void bn_silu_kernel(
    float* __restrict__ out, const float* __restrict__ bn)
{
    __shared__ float s[128];
    if (threadIdx.x < 128) s[threadIdx.x] = bn[threadIdx.x];
    __syncthreads();
    f32x4* o4 = (f32x4*)out;
    const long M4 = (long)NPTS * 16;
    for (long i = (long)blockIdx.x * 256 + threadIdx.x; i < M4; i += (long)gridDim.x * 256) {
        const int c0 = ((int)i & 15) << 2;
        f32x4 v = __builtin_nontemporal_load(o4 + i);
#pragma unroll
        for (int j = 0; j < 4; ++j) {
            const float y = v[j] * s[c0 + j] + s[64 + c0 + j];
            v[j] = y * (1.0f / (1.0f + __expf(-y)));
        }
        __builtin_nontemporal_store(v, o4 + i);
    }
}

extern "C" void kernel_launch(void* const* d_in, const int* in_sizes, int n_in,
                              void* d_out, int out_size, void* d_ws, size_t ws_size,
                              hipStream_t stream)
{
    const float* feats     = (const float*)d_in[0];
    const float* time_emb  = (const float*)d_in[1];
    const float* W         = (const float*)d_in[2];
    /* d_in[3] = bias: cancels exactly under training-mode BN -> unused */
    const float* gamma     = (const float*)d_in[4];
    const float* beta      = (const float*)d_in[5];
    const int*   batch_idx = (const int*)d_in[6];
    const int*   nbr_idx   = (const int*)d_in[7];
    const int*   nbr_valid = (const int*)d_in[8];
    float* out = (float*)d_out;

    char* ws = (char*)d_ws;
    size_t off = 0;
    __bf16* xb  = (__bf16*)(ws + off); off += (size_t)(NPTS + 1) * 64 * 2;   // 128.0 MB
    __bf16* wbt = (__bf16*)(ws + off); off += (size_t)KOFF * 4096 * 2;       // 216 KB
    float* partials = (float*)(ws + off); off += (size_t)NWAVES * 128 * 4;   // 16.0 MB
    float* p2   = (float*)(ws + off); off += 128 * 128 * 4;                  // 64 KB
    float* bn   = (float*)(ws + off); off += 512;

    hipLaunchKernelGGL(build_x_kernel, dim3(62501), dim3(256), 0, stream,
                       feats, time_emb, batch_idx, xb);
    hipLaunchKernelGGL(wtrans_kernel, dim3(432), dim3(256), 0, stream, W, wbt);
    hipLaunchKernelGGL(conv_kernel, dim3(NWG_CONV), dim3(256), 0, stream,
                       xb, wbt, nbr_idx, nbr_valid, out, partials);
    hipLaunchKernelGGL(bn_pass1, dim3(128), dim3(256), 0, stream, partials, p2);
    hipLaunchKernelGGL(bn_pass2, dim3(1), dim3(128), 0, stream, p2, gamma, beta, bn);
    hipLaunchKernelGGL(bn_silu_kernel, dim3(2048), dim3(256), 0, stream, out, bn);
}